// Round 1
// baseline (133.313 us; speedup 1.0000x reference)
//
#include <hip/hip_runtime.h>
#include <math.h>

#define N_COLS 1024
#define TPR    16      // threads (chunks) per row
#define CHUNK  64      // columns per thread
#define ROWS_PER_BLOCK 16
#define NRINGS 8

// Fused encoder(4 rings) -> blend -> decoder(4 rings).
// Each ring: x[:,k] <- c*x[:,k]-s*x[:,k+1]; x[:,k+1] <- s*x[:,k]+c*x[:,k+1]
// for k = n-1..0 (ring plane (k, k+1 mod n)).  Rewritten as an affine carry
// recurrence, parallelized across 16 lanes/row with an affine suffix scan.
__global__ __launch_bounds__(256, 2)
void ClassicalEncoderDecoder_57080115363917_kernel(
        const float* __restrict__ x,
        const float* __restrict__ ae,
        const float* __restrict__ ad,
        const float* __restrict__ hw,
        const float* __restrict__ hs,
        float* __restrict__ out, int B)
{
    // cs table layout [ring][j][t] (t fastest) so the 16 lanes of a group
    // read stride-8B -> banks 2t,2t+1 -> all 32 banks once, conflict-free,
    // 4-way broadcast across the 4 row-groups of the wave.
    __shared__ float2 s_cs[NRINGS * CHUNK * TPR];   // 64 KB
    __shared__ float  s_A [NRINGS * TPR];           // per-chunk prod(-s)
    __shared__ float2 s_aux[NRINGS];                // real (c,s) at k=1023

    const int tid = threadIdx.x;

    // ---------------- table setup (angle-only, once per block) -------------
    for (int i = 0; i < 32; ++i) {
        int idx = i * 256 + tid;            // 0..8191 = ring*1024 + k
        int r   = idx >> 10;
        int k   = idx & 1023;
        const float* ang = (r < 4) ? (ae + (r << 10)) : (ad + ((r - 4) << 10));
        float a = ang[k];
        float sv, cv;
        sincosf(a, &sv, &cv);
        int t = k >> 6, j = k & 63;
        float2 e = make_float2(cv, sv);
        if (k == 1023) {                    // step k=1023 doesn't exist:
            s_aux[r] = e;                   // keep real values for Cinit/x0n,
            e = make_float2(0.f, -1.f);     // doctored entry = exact no-op
        }
        s_cs[(r * CHUNK + j) * TPR + t] = e;
    }
    __syncthreads();
    if (tid < NRINGS * TPR) {
        int r = tid >> 4, t = tid & 15;
        float p = 1.f;
        for (int j = 0; j < CHUNK; ++j) p *= -s_cs[(r * CHUNK + j) * TPR + t].y;
        s_A[tid] = p;                       // chunk transfer coefficient
    }
    __syncthreads();

    // ---------------- per-row state --------------------------------------
    const int lane      = tid & 63;
    const int g         = lane >> 4;        // row-group within wave (4 rows/wave)
    const int t         = lane & 15;        // chunk index within row
    const int groupBase = lane & 48;        // first lane of this group
    const int row       = blockIdx.x * ROWS_PER_BLOCK + (tid >> 6) * 4 + g;

    const float* xr = x + (size_t)row * N_COLS + t * CHUNK;
    float y[CHUNK];
    #pragma unroll
    for (int i = 0; i < 16; ++i) {
        float4 v = ((const float4*)xr)[i];
        y[4*i+0] = v.x; y[4*i+1] = v.y; y[4*i+2] = v.z; y[4*i+3] = v.w;
    }

    const float w   = 1.f / (1.f + expf(-hw[0]));
    const float omw = 1.f - w;

    for (int r = 0; r < NRINGS; ++r) {
        if (r == 4) {
            // bottleneck = (1-w)*b + w*hidden_state ; write output 0
            float4* ob = (float4*)(out + (size_t)row * N_COLS + t * CHUNK);
            const float4* hp = (const float4*)(hs + t * CHUNK);
            #pragma unroll
            for (int i = 0; i < 16; ++i) {
                float4 h = hp[i];
                float4 bn;
                bn.x = fmaf(omw, y[4*i+0], w * h.x);
                bn.y = fmaf(omw, y[4*i+1], w * h.y);
                bn.z = fmaf(omw, y[4*i+2], w * h.z);
                bn.w = fmaf(omw, y[4*i+3], w * h.w);
                ob[i] = bn;
                y[4*i+0] = bn.x; y[4*i+1] = bn.y; y[4*i+2] = bn.z; y[4*i+3] = bn.w;
            }
        }

        const float2* csr = s_cs + r * CHUNK * TPR;
        const float2  cN  = s_aux[r];

        // ring-start specials: need original y[0] (lane t=0) and y[1023] (t=15)
        float y0 = __shfl(y[0],  groupBase);
        float yN = __shfl(y[63], groupBase + 15);
        float Cinit = cN.x * yN - cN.y * y0;          // carry entering chain
        float x0n   = fmaf(cN.y, yN, cN.x * y0);      // updated slot 0
        if (t == 0) y[0] = x0n;  // makes step k=0 a normal chain step

        // ---- pass 1: local chain with carry_in = 0 -> B_t, z_partial ----
        float carry = 0.f;
        float ztmp  = 0.f;       // z for slot 64t+64 (handed to lane t+1)
        #pragma unroll
        for (int j = CHUNK - 1; j >= 0; --j) {
            float2 cs = csr[j * TPR + t];
            float z   = fmaf(cs.y, y[j], cs.x * carry);
            carry     = fmaf(-cs.y, carry, cs.x * y[j]);
            if (j == CHUNK - 1) ztmp = z; else y[j + 1] = z;  // y[j+1] dead
        }

        // ---- affine suffix scan over the 16-lane group (carry: 15 -> 0) ----
        float sa = s_A[r * TPR + t], sb = carry;      // f_t(x) = sa*x + sb
        #pragma unroll
        for (int d = 1; d < 16; d <<= 1) {
            float a2 = __shfl_down(sa, d);
            float b2 = __shfl_down(sb, d);
            if (t + d < 16) { sb = fmaf(sa, b2, sb); sa *= a2; }
        }
        float ea = __shfl_down(sa, 1);                // exclusive = S_{t+1}
        float eb = __shfl_down(sb, 1);
        float z0  = fmaf(sa, Cinit, sb);              // lane0 inclusive = z[0]
        float Cin = (t == 15) ? Cinit : fmaf(ea, Cinit, eb);

        // ---- pass 2: independent fix-up z += (c_j * P_j) * Cin ----
        float P = 1.f;
        #pragma unroll
        for (int j = CHUNK - 1; j >= 0; --j) {
            float2 cs = csr[j * TPR + t];
            float f = cs.x * P;
            P = -cs.y * P;
            if (j == CHUNK - 1) ztmp = fmaf(f, Cin, ztmp);
            else                y[j + 1] = fmaf(f, Cin, y[j + 1]);
        }

        // slot 64t comes from lane t-1's top output; lane0 slot0 = z[0]
        float up = __shfl_up(ztmp, 1);
        y[0] = (t == 0) ? z0 : up;
    }

    // ---------------- write output 1 (decoder result) ---------------------
    float4* oo = (float4*)(out + (size_t)B * N_COLS + (size_t)row * N_COLS + t * CHUNK);
    #pragma unroll
    for (int i = 0; i < 16; ++i) {
        float4 v;
        v.x = y[4*i+0]; v.y = y[4*i+1]; v.z = y[4*i+2]; v.w = y[4*i+3];
        oo[i] = v;
    }
}

extern "C" void kernel_launch(void* const* d_in, const int* in_sizes, int n_in,
                              void* d_out, int out_size, void* d_ws, size_t ws_size,
                              hipStream_t stream) {
    const float* x  = (const float*)d_in[0];
    const float* ae = (const float*)d_in[1];
    const float* ad = (const float*)d_in[2];
    const float* hw = (const float*)d_in[3];
    const float* hs = (const float*)d_in[4];
    float* out = (float*)d_out;

    const int B = in_sizes[0] / N_COLS;          // 8192
    dim3 grid(B / ROWS_PER_BLOCK), block(256);   // 512 blocks x 256 thr
    hipLaunchKernelGGL(ClassicalEncoderDecoder_57080115363917_kernel,
                       grid, block, 0, stream, x, ae, ad, hw, hs, out, B);
}